// Round 20
// baseline (148.555 us; speedup 1.0000x reference)
//
#include <hip/hip_runtime.h>

typedef unsigned short u16;

#define DEV static __device__ __forceinline__

DEV float bf2f(u16 v) { unsigned x = ((unsigned)v) << 16; return __uint_as_float(x); }
DEV u16 f2bf(float f) {
    unsigned x = __float_as_uint(f);
    unsigned r = (x + 0x7fffu + ((x >> 16) & 1u)) >> 16;
    return (u16)r;
}

constexpr int BATCH = 2;
constexpr int CH    = 384;
constexpr int HH    = 96;
constexpr int WW    = 96;
constexpr int NTOK  = HH * WW;      // 9216
constexpr int GW    = 48;
constexpr int G     = GW * GW;      // 2304 pooled tokens
constexpr int HEADS = 6;
constexpr int NT    = G / 64;       // 36 key-tiles
constexpr float SCALE = 0.17677669529663687f;          // 32^-0.5
constexpr float QKSCALE = 0.25503497438034225f;        // SCALE * log2(e)

typedef __attribute__((ext_vector_type(8)))  short short8v;   // 8 bf16
typedef __attribute__((ext_vector_type(4)))  float f32x4;
typedef __attribute__((ext_vector_type(16))) float f32x16;

DEV f32x4 mfma16(short8v a, short8v b, f32x4 c) {
    return __builtin_amdgcn_mfma_f32_16x16x32_bf16(a, b, c, 0, 0, 0);
}
DEV f32x16 mfma32(short8v a, short8v b, f32x16 c) {
    return __builtin_amdgcn_mfma_f32_32x32x16_bf16(a, b, c, 0, 0, 0);
}

DEV unsigned cvtpk_bf16(float a, float b) {
    unsigned r;
    asm("v_cvt_pk_bf16_f32 %0, %1, %2" : "=v"(r) : "v"(a), "v"(b));
    return r;
}

DEV float exp2fast(float x) {
    float r;
    asm("v_exp_f32 %0, %1" : "=v"(r) : "v"(x));
    return r;
}

DEV float rcpfast(float x) {
    float r;
    asm("v_rcp_f32 %0, %1" : "=v"(r) : "v"(x));
    return r;
}

DEV void permswap(unsigned& a, unsigned& b) {
    asm("v_permlane32_swap_b32 %0, %1" : "+v"(a), "+v"(b));
}

DEV void unpack8(uint4 u, float* f) {
    unsigned a0 = u.x, a1 = u.y, a2 = u.z, a3 = u.w;
    f[0] = bf2f((u16)(a0 & 0xffffu)); f[1] = bf2f((u16)(a0 >> 16));
    f[2] = bf2f((u16)(a1 & 0xffffu)); f[3] = bf2f((u16)(a1 >> 16));
    f[4] = bf2f((u16)(a2 & 0xffffu)); f[5] = bf2f((u16)(a2 >> 16));
    f[6] = bf2f((u16)(a3 & 0xffffu)); f[7] = bf2f((u16)(a3 >> 16));
}

// ---------------------------------------------------------------------------
// prep: fused xT transpose [0,6912) + pool_xpose [6912,8640) + wtrans [8640,9144)
// ---------------------------------------------------------------------------
__global__ __launch_bounds__(256) void prep(const float* __restrict__ x,
        const float* __restrict__ W0, const float* __restrict__ W1,
        const float* __restrict__ W2, const float* __restrict__ W3,
        const float* __restrict__ W4,
        u16* __restrict__ xT, u16* __restrict__ xpool,
        u16* __restrict__ D0, u16* __restrict__ D1, u16* __restrict__ D2,
        u16* __restrict__ D3, u16* __restrict__ D4) {
    __shared__ float ts[32][33];
    int tid = threadIdx.x;
    int id = blockIdx.x;
    if (id < 6912) {
        int cx = id % 288, cy = (id / 288) % 12, b = id / 3456;
        int c0 = cx * 32, r0 = cy * 32;
        int row = tid >> 3, cg = tid & 7;
        float4 v = *(const float4*)&x[(size_t)b * CH * NTOK + (size_t)(r0 + row) * NTOK + c0 + cg * 4];
        ts[row][cg * 4 + 0] = v.x; ts[row][cg * 4 + 1] = v.y;
        ts[row][cg * 4 + 2] = v.z; ts[row][cg * 4 + 3] = v.w;
        __syncthreads();
        int cc = tid >> 3, rg = tid & 7;
        uint2 u;
        u.x = (unsigned)f2bf(ts[rg * 4 + 0][cc]) | ((unsigned)f2bf(ts[rg * 4 + 1][cc]) << 16);
        u.y = (unsigned)f2bf(ts[rg * 4 + 2][cc]) | ((unsigned)f2bf(ts[rg * 4 + 3][cc]) << 16);
        *(uint2*)&xT[(size_t)b * NTOK * CH + (size_t)(c0 + cc) * CH + r0 + rg * 4] = u;
    } else if (id < 8640) {
        int t = id - 6912;
        int mx = t % 72, cy = (t / 72) % 12, b = t / 864;
        int m0 = mx * 32, c0 = cy * 32;
        int cc = tid >> 3, mg = tid & 7;
        const float* xb = x + ((size_t)b * CH + c0 + cc) * NTOK;
        #pragma unroll
        for (int i = 0; i < 4; i++) {
            int m = m0 + mg * 4 + i;
            int gy = m / GW, gx = m - gy * GW;
            const float* p = xb + gy * 2 * WW + gx * 2;
            ts[cc][mg * 4 + i] = 0.25f * (p[0] + p[1] + p[WW] + p[WW + 1]);
        }
        __syncthreads();
        int mm = tid >> 3, cg = tid & 7;
        uint2 u;
        u.x = (unsigned)f2bf(ts[cg * 4 + 0][mm]) | ((unsigned)f2bf(ts[cg * 4 + 1][mm]) << 16);
        u.y = (unsigned)f2bf(ts[cg * 4 + 2][mm]) | ((unsigned)f2bf(ts[cg * 4 + 3][mm]) << 16);
        *(uint2*)&xpool[((size_t)b * G + m0 + mm) * CH + c0 + cg * 4] = u;
    } else {
        int wid = id - 8640;
        const float* src; u16* dst; int R, C; float scale; int cx, cy;
        if (wid < 216)      { src = W0; dst = D0; R = 384; C = 576; scale = 1.f;     cx = wid % 18; cy = wid / 18; }
        else if (wid < 288) { src = W1; dst = D1; R = 384; C = 192; scale = QKSCALE; int t = wid - 216; cx = t % 6;  cy = t / 6; }
        else if (wid < 432) { src = W2; dst = D2; R = 384; C = 384; scale = 1.f;     int t = wid - 288; cx = t % 12; cy = t / 12; }
        else if (wid < 468) { src = W3; dst = D3; R = 192; C = 192; scale = 1.f;     int t = wid - 432; cx = t % 6;  cy = t / 6; }
        else                { src = W4; dst = D4; R = 192; C = 192; scale = 1.f;     int t = wid - 468; cx = t % 6;  cy = t / 6; }
        int c0 = cx * 32, r0 = cy * 32;
        int row = tid >> 3, cg = tid & 7;
        float4 v = *(const float4*)&src[(size_t)(r0 + row) * C + c0 + cg * 4];
        ts[row][cg * 4 + 0] = v.x; ts[row][cg * 4 + 1] = v.y;
        ts[row][cg * 4 + 2] = v.z; ts[row][cg * 4 + 3] = v.w;
        __syncthreads();
        int cc = tid >> 3, rg = tid & 7;
        uint2 u;
        u.x = (unsigned)f2bf(scale * ts[rg * 4 + 0][cc]) | ((unsigned)f2bf(scale * ts[rg * 4 + 1][cc]) << 16);
        u.y = (unsigned)f2bf(scale * ts[rg * 4 + 2][cc]) | ((unsigned)f2bf(scale * ts[rg * 4 + 3][cc]) << 16);
        *(uint2*)&dst[(size_t)(c0 + cc) * R + r0 + rg * 4] = u;
    }
}

// ---------------------------------------------------------------------------
// gemm64_body: 64x64 tile, BK=64. acc[qg] = sum_k Pr[p][k]*Qr[q][k].
// ---------------------------------------------------------------------------
template<int K>
DEV void gemm64_body(const u16* __restrict__ Pr, const u16* __restrict__ Qr,
                     u16* pt, u16* qt, int tid, f32x4 acc[4]) {
    int w = tid >> 6, lane = tid & 63;
    int l15 = lane & 15, q4 = lane >> 4;
    int lr = tid >> 2, lc = tid & 3;
    const f32x4 zero4 = {0.f, 0.f, 0.f, 0.f};
    acc[0] = zero4; acc[1] = zero4; acc[2] = zero4; acc[3] = zero4;
    uint4 pv0 = *(const uint4*)&Pr[(size_t)lr * K + lc * 8];
    uint4 pv1 = *(const uint4*)&Pr[(size_t)lr * K + 32 + lc * 8];
    uint4 qv0 = *(const uint4*)&Qr[(size_t)lr * K + lc * 8];
    uint4 qv1 = *(const uint4*)&Qr[(size_t)lr * K + 32 + lc * 8];
    for (int k0 = 0; k0 < K; k0 += 64) {
        __syncthreads();
        *(uint4*)&pt[lr * 72 + lc * 8] = pv0;
        *(uint4*)&pt[lr * 72 + 32 + lc * 8] = pv1;
        *(uint4*)&qt[lr * 72 + lc * 8] = qv0;
        *(uint4*)&qt[lr * 72 + 32 + lc * 8] = qv1;
        if (k0 + 64 < K) {
            pv0 = *(const uint4*)&Pr[(size_t)lr * K + k0 + 64 + lc * 8];
            pv1 = *(const uint4*)&Pr[(size_t)lr * K + k0 + 96 + lc * 8];
            qv0 = *(const uint4*)&Qr[(size_t)lr * K + k0 + 64 + lc * 8];
            qv1 = *(const uint4*)&Qr[(size_t)lr * K + k0 + 96 + lc * 8];
        }
        __syncthreads();
        #pragma unroll
        for (int half = 0; half < 2; half++) {
            short8v pa = *(const short8v*)&pt[(w * 16 + l15) * 72 + half * 32 + q4 * 8];
            #pragma unroll
            for (int qg = 0; qg < 4; qg++) {
                short8v qb = *(const short8v*)&qt[(qg * 16 + l15) * 72 + half * 32 + q4 * 8];
                acc[qg] = mfma16(pa, qb, acc[qg]);
            }
        }
    }
}

// ---------------------------------------------------------------------------
// gemm_all: tokf 64x128 [0,1728) + kF [1728,1944) + vF [1944,2160). K=384.
// tokf: wave = 16p x 128q -> 9 ds_reads per 8 MFMA; half the blocks/barriers.
// p-span stays 64 (write locality preserved; 128-p span thrashed L2 r8/r12).
// ---------------------------------------------------------------------------
__global__ __launch_bounds__(256) void gemm_all(const u16* __restrict__ WT768,
        const u16* __restrict__ xT, const u16* __restrict__ WlkT,
        const u16* __restrict__ WvT, const u16* __restrict__ xpool,
        u16* __restrict__ tokf, u16* __restrict__ kF, u16* __restrict__ vF) {
    __shared__ u16 pt[64 * 72];
    __shared__ u16 qt[128 * 72];
    int tid = threadIdx.x, id = blockIdx.x;
    int w = tid >> 6, lane = tid & 63, l15 = lane & 15, q4 = lane >> 4;
    const f32x4 zero4 = {0.f, 0.f, 0.f, 0.f};
    if (id < 1728) {
        // tokf: 64p x 128q tile, BK=64
        int px = id % 12, qy = (id / 12) % 72, b = id / 864;
        const u16* Pr = WT768 + (size_t)px * 64 * CH;
        const u16* Qr = xT + ((size_t)b * NTOK + qy * 128) * CH;
        int lr = tid >> 2, lc = tid & 3;       // pt: 64 rows, 2 uint4/thr
        int qr = tid >> 1, qc = tid & 1;       // qt: 128 rows, 4 uint4/thr
        f32x4 acc[8];
        #pragma unroll
        for (int j = 0; j < 8; j++) acc[j] = zero4;
        uint4 pv0 = *(const uint4*)&Pr[(size_t)lr * CH + lc * 8];
        uint4 pv1 = *(const uint4*)&Pr[(size_t)lr * CH + 32 + lc * 8];
        uint4 qv[4];
        #pragma unroll
        for (int i = 0; i < 4; i++)
            qv[i] = *(const uint4*)&Qr[(size_t)qr * CH + qc * 32 + i * 8];
        for (int k0 = 0; k0 < CH; k0 += 64) {
            __syncthreads();
            *(uint4*)&pt[lr * 72 + lc * 8] = pv0;
            *(uint4*)&pt[lr * 72 + 32 + lc * 8] = pv1;
            #pragma unroll
            for (int i = 0; i < 4; i++)
                *(uint4*)&qt[qr * 72 + qc * 32 + i * 8] = qv[i];
            if (k0 + 64 < CH) {
                pv0 = *(const uint4*)&Pr[(size_t)lr * CH + k0 + 64 + lc * 8];
                pv1 = *(const uint4*)&Pr[(size_t)lr * CH + k0 + 96 + lc * 8];
                #pragma unroll
                for (int i = 0; i < 4; i++)
                    qv[i] = *(const uint4*)&Qr[(size_t)qr * CH + k0 + 64 + qc * 32 + i * 8];
            }
            __syncthreads();
            #pragma unroll
            for (int half = 0; half < 2; half++) {
                short8v pa = *(const short8v*)&pt[(w * 16 + l15) * 72 + half * 32 + q4 * 8];
                #pragma unroll
                for (int j = 0; j < 8; j++) {
                    short8v qb = *(const short8v*)&qt[(j * 16 + l15) * 72 + half * 32 + q4 * 8];
                    acc[j] = mfma16(pa, qb, acc[j]);
                }
            }
        }
        #pragma unroll
        for (int j = 0; j < 8; j++) {
            int q = qy * 128 + j * 16 + l15;
            int p = px * 64 + w * 16 + q4 * 4;
            uint2 pk;
            pk.x = (unsigned)f2bf(acc[j][0]) | ((unsigned)f2bf(acc[j][1]) << 16);
            pk.y = (unsigned)f2bf(acc[j][2]) | ((unsigned)f2bf(acc[j][3]) << 16);
            *(uint2*)&tokf[((size_t)b * NTOK + q) * 768 + p] = pk;
        }
    } else if (id < 1944) {
        int u = id - 1728;
        int px = u % 3, qy = (u / 3) % 36, b = u / 108;
        f32x4 acc[4];
        gemm64_body<CH>(WlkT + (size_t)px * 64 * CH,
                        xpool + ((size_t)b * G + qy * 64) * CH, pt, qt, tid, acc);
        #pragma unroll
        for (int qg = 0; qg < 4; qg++) {
            int m = qy * 64 + qg * 16 + l15;
            int d = px * 64 + w * 16 + q4 * 4;
            int h = d >> 5, dh = (d >> 4) & 1, hi2 = (d >> 3) & 1;
            int kh = (m >> 5) & 1, tile = m >> 6, slot = kh * 2 + dh;
            int lane2 = (m & 31) + 32 * hi2;
            size_t addr = ((((size_t)(b * HEADS + h) * NT + tile) * 4 + slot) * 64 + lane2) * 8 + (d & 7);
            uint2 pk;
            pk.x = (unsigned)f2bf(acc[qg][0]) | ((unsigned)f2bf(acc[qg][1]) << 16);
            pk.y = (unsigned)f2bf(acc[qg][2]) | ((unsigned)f2bf(acc[qg][3]) << 16);
            *(uint2*)&kF[addr] = pk;
        }
    } else {
        int u = id - 1944;
        int px = u % 36, qy = (u / 36) % 3, b = u / 108;
        f32x4 acc[4];
        gemm64_body<CH>(xpool + ((size_t)b * G + px * 64) * CH,
                        WvT + (size_t)qy * 64 * CH, pt, qt, tid, acc);
        #pragma unroll
        for (int qg = 0; qg < 4; qg++) {
            int jj = qy * 64 + qg * 16 + l15;
            int m = px * 64 + w * 16 + q4 * 4;
            int h = jj >> 5, d31 = jj & 31;
            int tile = m >> 6, slot = (m >> 4) & 3, hi2 = (m >> 3) & 1;
            int lane2 = d31 + 32 * hi2;
            size_t addr = ((((size_t)(b * HEADS + h) * NT + tile) * 4 + slot) * 64 + lane2) * 8 + (m & 7);
            uint2 pk;
            pk.x = (unsigned)f2bf(acc[qg][0]) | ((unsigned)f2bf(acc[qg][1]) << 16);
            pk.y = (unsigned)f2bf(acc[qg][2]) | ((unsigned)f2bf(acc[qg][3]) << 16);
            *(uint2*)&vF[addr] = pk;
        }
    }
}

// ---------------------------------------------------------------------------
// mega_attn: 256 thr, 5760 blocks interleaved 3 lo : 2 hi via id%5.
// lo (3456): 4 waves = 4-way key split, 9 tiles, 32 q/block; MFMA row-sums;
//   kb A/B register prefetch; s_setprio(1) around per-tile compute (T5).
// hi (2304): TWO windows per block — threads 0-127 / 128-255 each own one.
// NOTE r16: __launch_bounds__(256,8) spills (VGPR->32, 9x slower). Keep (,4).
// ---------------------------------------------------------------------------
__global__ __launch_bounds__(256, 4) void mega_attn(const u16* __restrict__ tokf,
        const u16* __restrict__ kF, const u16* __restrict__ vF,
        u16* __restrict__ hi_ao, u16* __restrict__ lo_ao) {
    __shared__ float smem[4992];
    int tid = threadIdx.x;
    int grp = blockIdx.x / 5, rem = blockIdx.x % 5;
    const f32x16 zero16 = {0.f,0.f,0.f,0.f,0.f,0.f,0.f,0.f,0.f,0.f,0.f,0.f,0.f,0.f,0.f,0.f};

    if (rem < 3) {
        int lid = grp * 3 + rem;              // 0..3455
        int lane = tid & 63, kq = tid >> 6;   // key-quarter 0..3
        int l31 = lane & 31, hi = lane >> 5;
        int qt = lid % 288, h = (lid / 288) % HEADS, b = lid / 1728;

        const short8v ones = {(short)0x3F80, (short)0x3F80, (short)0x3F80, (short)0x3F80,
                              (short)0x3F80, (short)0x3F80, (short)0x3F80, (short)0x3F80};

        short8v qb0, qb1;
        {
            int nq = qt * 32 + l31;
            const u16* qrow = &tokf[((size_t)b * NTOK + nq) * 768 + 576 + h * 32];
            qb0 = *(const short8v*)&qrow[hi * 8];
            qb1 = *(const short8v*)&qrow[16 + hi * 8];
        }
        f32x16 accO = zero16, accL = zero16;

        const u16* kp = kF + ((size_t)(b * HEADS + h) * NT + kq * 9) * 2048 + lane * 8;
        const u16* vp = vF + ((size_t)(b * HEADS + h) * NT + kq * 9) * 2048 + lane * 8;

        auto process = [&](const short8v* kb, const u16* vc) {
            short8v vb0 = *(const short8v*)(vc);
            short8v vb1 = *(const short8v*)(vc + 512);
            short8v vb2 = *(const short8v*)(vc + 1024);
            short8v vb3 = *(const short8v*)(vc + 1536);

            __builtin_amdgcn_s_setprio(1);
            f32x16 s0 = mfma32(kb[0], qb0, zero16);
            s0 = mfma32(kb[1], qb1, s0);
            unsigned pk0[8];
            #pragma unroll
            for (int i = 0; i < 8; i++)
                pk0[i] = cvtpk_bf16(exp2fast(s0[2 * i]), exp2fast(s0[2 * i + 1]));
            permswap(pk0[0], pk0[2]);
            permswap(pk0[1], pk0[3]);
            permswap(pk0[4], pk0[6]);
            permswap(pk0[5], pk0[7]);

            f32x16 s1 = mfma32(kb[2], qb0, zero16);
            s1 = mfma32(kb[3], qb1, s1);
            unsigned pk1[8];
            #pragma unroll
            for (int i = 0; i < 8; i++)
                pk1[i] = cvtpk_bf16(exp2fast(s1[2 * i]), exp2fast(s1[2 * i + 1]));
            permswap(pk1[0], pk1[2]);
            permswap(pk1[1], pk1[3]);
            permswap(pk1[4], pk1[6]);
            permswap(pk1[5], pk1[7]);

            union { unsigned u[4]; short8v v; } pa;
            pa.u[0] = pk0[0]; pa.u[1] = pk0[1]; pa.u[2] = pk0[2]; pa.u[3] = pk0[3];
            accO = mfma32(pa.v, vb0, accO);
            accL = mfma32(pa.v, ones, accL);
            pa.u[0] = pk0[4]; pa.u[1] = pk0[5]; pa.u[2] = pk0[6]; pa.u[3] = pk0[7];
            accO = mfma32(pa.v, vb1, accO);
            accL = mfma32(pa.v, ones, accL);
            pa.u[0] = pk1[0]; pa.u[1] = pk1[1]; pa.u[2] = pk1[2]; pa.u[3] = pk1[3];
            accO = mfma32(pa.v, vb2, accO);
            accL = mfma32(pa.v, ones, accL);
            pa.u[0] = pk1[4]; pa.u[1] = pk1[5]; pa.u[2] = pk1[6]; pa.u[3] = pk1[7];
            accO = mfma32(pa.v, vb3, accO);
            accL = mfma32(pa.v, ones, accL);
            __builtin_amdgcn_s_setprio(0);
        };

        short8v kbA[4], kbB[4];
        #pragma unroll
        for (int sl = 0; sl < 4; sl++) kbA[sl] = *(const short8v*)&kp[sl * 512];

        #pragma unroll
        for (int i = 0; i < 4; i++) {
            {   // even tile t=2i: uses kbA, prefetch kbB(t=2i+1)
                const u16* kn = kp + (size_t)(2 * i + 1) * 2048;
                #pragma unroll
                for (int sl = 0; sl < 4; sl++) kbB[sl] = *(const short8v*)&kn[sl * 512];
                process(kbA, vp + (size_t)(2 * i) * 2048);
            }
            {   // odd tile t=2i+1: uses kbB, prefetch kbA(t=2i+2)
                const u16* kn = kp + (size_t)(2 * i + 2) * 2048;
                #pragma unroll
                for (int sl = 0; sl < 4; sl++) kbA[sl] = *(const short8v*)&kn[sl * 512];
                process(kbB, vp + (size_t)(2 * i + 1) * 2048);
            }
        }
        process(kbA, vp + (size_t)8 * 2048);   // t=8

        // ---- merge 4 key-quarter waves (pure add: no-max softmax) ----
        float* mO = smem;            // [3][16][64] transposed, conflict-free
        float* mL = smem + 3072;     // [3][32]  (accL lane-redundant per half)
        if (kq) {
            int base = (kq - 1) * 1024;
            #pragma unroll
            for (int r = 0; r < 16; r++) mO[base + r * 64 + lane] = accO[r];
            if (l31 == 0) {
                #pragma unroll
                for (int r = 0; r < 16; r++) mL[(kq - 1) * 32 + hi * 16 + r] = accL[r];
            }
        }
        __syncthreads();
        if (kq == 0) {
            #pragma unroll
            for (int w2 = 0; w2 < 3; w2++) {
                int base = w2 * 1024;
                #pragma unroll
                for (int r = 0; r < 16; r++) {
                    accO[r] += mO[base + r * 64 + lane];
                    accL[r] += mL[w2 * 32 + hi * 16 + r];
                }
            }
            #pragma unroll
            for (int r = 0; r < 16; r++) {
                int qr = (r & 3) + 8 * (r >> 2) + 4 * hi;
                int n = qt * 32 + qr;
                lo_ao[((size_t)b * NTOK + n) * 192 + h * 32 + l31] =
                    f2bf(accO[r] * rcpfast(accL[r]));
            }
        }
    } else {
        // ---- hi: 2 windows per block, threads 0-127 / 128-255 ----
        int tid2 = tid & 127, win = tid >> 7;
        int bg = grp * 4 + (rem - 3) * 2 + win;   // 0..4607
        int b = bg / G, g = bg % G;
        int gy = g / GW, gx = g % GW;
        float* s = smem + win * 2496;
        float (*sq)[576] = (float(*)[576])s;
        float* satt = s + 2304;   // [6][4][4]
        float* sp   = s + 2400;   // [6][4][4]

        for (int c = tid2; c < 288; c += 128) {
            int t = c / 72, j8 = c - t * 72;
            int n = (gy * 2 + (t >> 1)) * WW + gx * 2 + (t & 1);
            uint4 u = *(const uint4*)&tokf[((size_t)b * NTOK + n) * 768 + j8 * 8];
            unpack8(u, &sq[t][j8 * 8]);
        }
        __syncthreads();

        if (tid2 < 96) {
            int h = tid2 >> 4, tq = (tid2 >> 2) & 3, tm = tid2 & 3;
            const float* qp = &sq[tq][h * 32];
            const float* kp = &sq[tm][192 + h * 32];
            float s0 = 0, s1 = 0, s2 = 0, s3 = 0;
            #pragma unroll
            for (int d = 0; d < 32; d += 4) {
                s0 += qp[d] * kp[d];
                s1 += qp[d + 1] * kp[d + 1];
                s2 += qp[d + 2] * kp[d + 2];
                s3 += qp[d + 3] * kp[d + 3];
            }
            satt[h * 16 + tq * 4 + tm] = (s0 + s1 + s2 + s3) * SCALE;
        }
        __syncthreads();
        if (tid2 < 24) {
            int h = tid2 >> 2, t = tid2 & 3;
            float l0 = satt[h * 16 + t * 4 + 0], l1 = satt[h * 16 + t * 4 + 1];
            float l2 = satt[h * 16 + t * 4 + 2], l3 = satt[h * 16 + t * 4 + 3];
            float mx = fmaxf(fmaxf(l0, l1), fmaxf(l2, l3));
            float e0 = __expf(l0 - mx), e1 = __expf(l1 - mx);
            float e2 = __expf(l2 - mx), e3 = __expf(l3 - mx);
            float inv = 1.0f / (e0 + e1 + e2 + e3);
            sp[h * 16 + t * 4 + 0] = e0 * inv; sp[h * 16 + t * 4 + 1] = e1 * inv;
            sp[h * 16 + t * 4 + 2] = e2 * inv; sp[h * 16 + t * 4 + 3] = e3 * inv;
        }
        __syncthreads();
        {
            int t = tid2 >> 5, d = tid2 & 31;
            int n = (gy * 2 + (t >> 1)) * WW + gx * 2 + (t & 1);
            u16* op = &hi_ao[((size_t)b * NTOK + n) * 192];
            #pragma unroll
            for (int h = 0; h < HEADS; h++) {
                float o = sp[h * 16 + t * 4 + 0] * sq[0][384 + h * 32 + d]
                        + sp[h * 16 + t * 4 + 1] * sq[1][384 + h * 32 + d]
                        + sp[h * 16 + t * 4 + 2] * sq[2][384 + h * 32 + d]
                        + sp[h * 16 + t * 4 + 3] * sq[3][384 + h * 32 + d];
                op[h * 32 + d] = f2bf(o);
            }
        }
    }
}

// ---------------------------------------------------------------------------
// proj_both: both projections, grid (144, 3, 4): z = which*2 + b.
// ---------------------------------------------------------------------------
__global__ __launch_bounds__(256) void proj_both(const u16* __restrict__ hi_ao,
        const u16* __restrict__ lo_ao, const u16* __restrict__ WhpT,
        const u16* __restrict__ WlpT, const float* __restrict__ bh,
        const float* __restrict__ bl, float* __restrict__ out) {
    __shared__ u16 pt[64 * 72];
    __shared__ u16 qt[64 * 72];
    int tid = threadIdx.x;
    int z = blockIdx.z, which = z >> 1, b = z & 1;
    const u16* A = which ? lo_ao : hi_ao;
    const u16* W = which ? WlpT : WhpT;
    const float* bias = which ? bl : bh;
    int p0 = blockIdx.x * 64, q0 = blockIdx.y * 64;
    f32x4 acc[4];
    gemm64_body<192>(A + ((size_t)b * NTOK + p0) * 192, W + (size_t)q0 * 192,
                     pt, qt, tid, acc);
    int w = tid >> 6, lane = tid & 63, l15 = lane & 15, q4 = lane >> 4;
    #pragma unroll
    for (int qg = 0; qg < 4; qg++) {
        int q = q0 + qg * 16 + l15;
        int p = p0 + w * 16 + q4 * 4;
        float bb = bias[q];
        float4 o = make_float4(acc[qg][0] + bb, acc[qg][1] + bb,
                               acc[qg][2] + bb, acc[qg][3] + bb);
        *(float4*)&out[((size_t)b * CH + which * 192 + q) * NTOK + p] = o;
    }
}

// ---------------------------------------------------------------------------
extern "C" void kernel_launch(void* const* d_in, const int* in_sizes, int n_in,
                              void* d_out, int out_size, void* d_ws, size_t ws_size,
                              hipStream_t stream) {
    const float* x       = (const float*)d_in[0];
    const float* Wh_qkv  = (const float*)d_in[1];
    const float* Wh_proj = (const float*)d_in[2];
    const float* bh_proj = (const float*)d_in[3];
    const float* Wl_q    = (const float*)d_in[4];
    const float* Wl_kv   = (const float*)d_in[5];
    const float* Wl_proj = (const float*)d_in[6];
    const float* bl_proj = (const float*)d_in[7];
    float* out = (float*)d_out;

    // ---- workspace layout (bytes) ----
    char* ws = (char*)d_ws;
    u16*   tokf  = (u16*)ws;                               // [2][9216][768] bf16  28,311,552
    char*  ws1   = ws + (size_t)28311552;
    u16*   xT    = (u16*)ws1;                              // [2][9216][384] bf16  14,155,776
    u16*   hi_ao = (u16*)ws1;                              // overlay (xT dead after gemm_all)
    u16*   lo_ao = (u16*)(ws1 + 7077888);
    char*  ws2   = ws1 + (size_t)14155776;
    u16*   kF    = (u16*)ws2;                              // frag-major K  1,769,472
    u16*   vF    = (u16*)(ws2 + 1769472);                  // frag-major V  1,769,472
    char*  ws3   = ws2 + (size_t)7077888;
    u16*   xpool = (u16*)ws3;                              // [2][2304][384] bf16  3,538,944
    char*  ws4   = ws3 + (size_t)3538944;
    u16*   WT768 = (u16*)ws4;                              // [768][384]
    u16*   WlkvT = WT768 + 768 * 384;                      // [384][384]
    u16*   WhpT  = WlkvT + 384 * 384;                      // [192][192]
    u16*   WlpT  = WhpT + 192 * 192;                       // [192][192]
    u16*   WlkT  = WlkvT;                                  // rows 0..191
    u16*   WvT   = WlkvT + 192 * 384;                      // rows 192..383

    prep<<<dim3(9144), 256, 0, stream>>>(
        x, Wh_qkv, Wl_q, Wl_kv, Wh_proj, Wl_proj,
        xT, xpool, WT768, WT768 + 576 * 384, WlkvT, WhpT, WlpT);

    gemm_all<<<dim3(2160), 256, 0, stream>>>(
        WT768, xT, WlkT, WvT, xpool, tokf, kF, vF);

    mega_attn<<<dim3(5760), 256, 0, stream>>>(tokf, kF, vF, hi_ao, lo_ao);

    proj_both<<<dim3(144, 3, 4), 256, 0, stream>>>(
        hi_ao, lo_ao, WhpT, WlpT, bh_proj, bl_proj, out);
}

// Round 21
// 117.275 us; speedup vs baseline: 1.2667x; 1.2667x over previous
//
#include <hip/hip_runtime.h>

typedef unsigned short u16;

#define DEV static __device__ __forceinline__

DEV float bf2f(u16 v) { unsigned x = ((unsigned)v) << 16; return __uint_as_float(x); }
DEV u16 f2bf(float f) {
    unsigned x = __float_as_uint(f);
    unsigned r = (x + 0x7fffu + ((x >> 16) & 1u)) >> 16;
    return (u16)r;
}

constexpr int BATCH = 2;
constexpr int CH    = 384;
constexpr int HH    = 96;
constexpr int WW    = 96;
constexpr int NTOK  = HH * WW;      // 9216
constexpr int GW    = 48;
constexpr int G     = GW * GW;      // 2304 pooled tokens
constexpr int HEADS = 6;
constexpr int NT    = G / 64;       // 36 key-tiles
constexpr float SCALE = 0.17677669529663687f;          // 32^-0.5
constexpr float QKSCALE = 0.25503497438034225f;        // SCALE * log2(e)

typedef __attribute__((ext_vector_type(8)))  short short8v;   // 8 bf16
typedef __attribute__((ext_vector_type(4)))  float f32x4;
typedef __attribute__((ext_vector_type(16))) float f32x16;

DEV f32x4 mfma16(short8v a, short8v b, f32x4 c) {
    return __builtin_amdgcn_mfma_f32_16x16x32_bf16(a, b, c, 0, 0, 0);
}
DEV f32x16 mfma32(short8v a, short8v b, f32x16 c) {
    return __builtin_amdgcn_mfma_f32_32x32x16_bf16(a, b, c, 0, 0, 0);
}

DEV unsigned cvtpk_bf16(float a, float b) {
    unsigned r;
    asm("v_cvt_pk_bf16_f32 %0, %1, %2" : "=v"(r) : "v"(a), "v"(b));
    return r;
}

DEV float exp2fast(float x) {
    float r;
    asm("v_exp_f32 %0, %1" : "=v"(r) : "v"(x));
    return r;
}

DEV float rcpfast(float x) {
    float r;
    asm("v_rcp_f32 %0, %1" : "=v"(r) : "v"(x));
    return r;
}

DEV void permswap(unsigned& a, unsigned& b) {
    asm("v_permlane32_swap_b32 %0, %1" : "+v"(a), "+v"(b));
}

DEV void unpack8(uint4 u, float* f) {
    unsigned a0 = u.x, a1 = u.y, a2 = u.z, a3 = u.w;
    f[0] = bf2f((u16)(a0 & 0xffffu)); f[1] = bf2f((u16)(a0 >> 16));
    f[2] = bf2f((u16)(a1 & 0xffffu)); f[3] = bf2f((u16)(a1 >> 16));
    f[4] = bf2f((u16)(a2 & 0xffffu)); f[5] = bf2f((u16)(a2 >> 16));
    f[6] = bf2f((u16)(a3 & 0xffffu)); f[7] = bf2f((u16)(a3 >> 16));
}

// ---------------------------------------------------------------------------
// prep: fused xT transpose [0,6912) + pool_xpose [6912,8640) + wtrans [8640,9144)
// ---------------------------------------------------------------------------
__global__ __launch_bounds__(256) void prep(const float* __restrict__ x,
        const float* __restrict__ W0, const float* __restrict__ W1,
        const float* __restrict__ W2, const float* __restrict__ W3,
        const float* __restrict__ W4,
        u16* __restrict__ xT, u16* __restrict__ xpool,
        u16* __restrict__ D0, u16* __restrict__ D1, u16* __restrict__ D2,
        u16* __restrict__ D3, u16* __restrict__ D4) {
    __shared__ float ts[32][33];
    int tid = threadIdx.x;
    int id = blockIdx.x;
    if (id < 6912) {
        int cx = id % 288, cy = (id / 288) % 12, b = id / 3456;
        int c0 = cx * 32, r0 = cy * 32;
        int row = tid >> 3, cg = tid & 7;
        float4 v = *(const float4*)&x[(size_t)b * CH * NTOK + (size_t)(r0 + row) * NTOK + c0 + cg * 4];
        ts[row][cg * 4 + 0] = v.x; ts[row][cg * 4 + 1] = v.y;
        ts[row][cg * 4 + 2] = v.z; ts[row][cg * 4 + 3] = v.w;
        __syncthreads();
        int cc = tid >> 3, rg = tid & 7;
        uint2 u;
        u.x = (unsigned)f2bf(ts[rg * 4 + 0][cc]) | ((unsigned)f2bf(ts[rg * 4 + 1][cc]) << 16);
        u.y = (unsigned)f2bf(ts[rg * 4 + 2][cc]) | ((unsigned)f2bf(ts[rg * 4 + 3][cc]) << 16);
        *(uint2*)&xT[(size_t)b * NTOK * CH + (size_t)(c0 + cc) * CH + r0 + rg * 4] = u;
    } else if (id < 8640) {
        int t = id - 6912;
        int mx = t % 72, cy = (t / 72) % 12, b = t / 864;
        int m0 = mx * 32, c0 = cy * 32;
        int cc = tid >> 3, mg = tid & 7;
        const float* xb = x + ((size_t)b * CH + c0 + cc) * NTOK;
        #pragma unroll
        for (int i = 0; i < 4; i++) {
            int m = m0 + mg * 4 + i;
            int gy = m / GW, gx = m - gy * GW;
            const float* p = xb + gy * 2 * WW + gx * 2;
            ts[cc][mg * 4 + i] = 0.25f * (p[0] + p[1] + p[WW] + p[WW + 1]);
        }
        __syncthreads();
        int mm = tid >> 3, cg = tid & 7;
        uint2 u;
        u.x = (unsigned)f2bf(ts[cg * 4 + 0][mm]) | ((unsigned)f2bf(ts[cg * 4 + 1][mm]) << 16);
        u.y = (unsigned)f2bf(ts[cg * 4 + 2][mm]) | ((unsigned)f2bf(ts[cg * 4 + 3][mm]) << 16);
        *(uint2*)&xpool[((size_t)b * G + m0 + mm) * CH + c0 + cg * 4] = u;
    } else {
        int wid = id - 8640;
        const float* src; u16* dst; int R, C; float scale; int cx, cy;
        if (wid < 216)      { src = W0; dst = D0; R = 384; C = 576; scale = 1.f;     cx = wid % 18; cy = wid / 18; }
        else if (wid < 288) { src = W1; dst = D1; R = 384; C = 192; scale = QKSCALE; int t = wid - 216; cx = t % 6;  cy = t / 6; }
        else if (wid < 432) { src = W2; dst = D2; R = 384; C = 384; scale = 1.f;     int t = wid - 288; cx = t % 12; cy = t / 12; }
        else if (wid < 468) { src = W3; dst = D3; R = 192; C = 192; scale = 1.f;     int t = wid - 432; cx = t % 6;  cy = t / 6; }
        else                { src = W4; dst = D4; R = 192; C = 192; scale = 1.f;     int t = wid - 468; cx = t % 6;  cy = t / 6; }
        int c0 = cx * 32, r0 = cy * 32;
        int row = tid >> 3, cg = tid & 7;
        float4 v = *(const float4*)&src[(size_t)(r0 + row) * C + c0 + cg * 4];
        ts[row][cg * 4 + 0] = v.x; ts[row][cg * 4 + 1] = v.y;
        ts[row][cg * 4 + 2] = v.z; ts[row][cg * 4 + 3] = v.w;
        __syncthreads();
        int cc = tid >> 3, rg = tid & 7;
        uint2 u;
        u.x = (unsigned)f2bf(scale * ts[rg * 4 + 0][cc]) | ((unsigned)f2bf(scale * ts[rg * 4 + 1][cc]) << 16);
        u.y = (unsigned)f2bf(scale * ts[rg * 4 + 2][cc]) | ((unsigned)f2bf(scale * ts[rg * 4 + 3][cc]) << 16);
        *(uint2*)&dst[(size_t)(c0 + cc) * R + r0 + rg * 4] = u;
    }
}

// ---------------------------------------------------------------------------
// gemm64_body: 64x64 tile, BK=64 (6 barriers for K=384 vs 12 at BK=32).
// acc[qg] = sum_k Pr[p][k]*Qr[q][k], both row-major K. LDS rows padded to 72.
// (64x128 and 128x128 tiles both tested (r20/r12): 2-3x WORSE — per-block
//  output footprint >98KB thrashes per-XCD L2 -> HBM write amplification.)
// ---------------------------------------------------------------------------
template<int K>
DEV void gemm64_body(const u16* __restrict__ Pr, const u16* __restrict__ Qr,
                     u16* pt, u16* qt, int tid, f32x4 acc[4]) {
    int w = tid >> 6, lane = tid & 63;
    int l15 = lane & 15, q4 = lane >> 4;
    int lr = tid >> 2, lc = tid & 3;
    const f32x4 zero4 = {0.f, 0.f, 0.f, 0.f};
    acc[0] = zero4; acc[1] = zero4; acc[2] = zero4; acc[3] = zero4;
    uint4 pv0 = *(const uint4*)&Pr[(size_t)lr * K + lc * 8];
    uint4 pv1 = *(const uint4*)&Pr[(size_t)lr * K + 32 + lc * 8];
    uint4 qv0 = *(const uint4*)&Qr[(size_t)lr * K + lc * 8];
    uint4 qv1 = *(const uint4*)&Qr[(size_t)lr * K + 32 + lc * 8];
    for (int k0 = 0; k0 < K; k0 += 64) {
        __syncthreads();
        *(uint4*)&pt[lr * 72 + lc * 8] = pv0;
        *(uint4*)&pt[lr * 72 + 32 + lc * 8] = pv1;
        *(uint4*)&qt[lr * 72 + lc * 8] = qv0;
        *(uint4*)&qt[lr * 72 + 32 + lc * 8] = qv1;
        if (k0 + 64 < K) {
            pv0 = *(const uint4*)&Pr[(size_t)lr * K + k0 + 64 + lc * 8];
            pv1 = *(const uint4*)&Pr[(size_t)lr * K + k0 + 96 + lc * 8];
            qv0 = *(const uint4*)&Qr[(size_t)lr * K + k0 + 64 + lc * 8];
            qv1 = *(const uint4*)&Qr[(size_t)lr * K + k0 + 96 + lc * 8];
        }
        __syncthreads();
        #pragma unroll
        for (int half = 0; half < 2; half++) {
            short8v pa = *(const short8v*)&pt[(w * 16 + l15) * 72 + half * 32 + q4 * 8];
            #pragma unroll
            for (int qg = 0; qg < 4; qg++) {
                short8v qb = *(const short8v*)&qt[(qg * 16 + l15) * 72 + half * 32 + q4 * 8];
                acc[qg] = mfma16(pa, qb, acc[qg]);
            }
        }
    }
}

// ---------------------------------------------------------------------------
// gemm_all: tokf [0,3456) + kF [3456,3672) + vF [3672,3888), all K=384, 64x64.
// ---------------------------------------------------------------------------
__global__ __launch_bounds__(256) void gemm_all(const u16* __restrict__ WT768,
        const u16* __restrict__ xT, const u16* __restrict__ WlkT,
        const u16* __restrict__ WvT, const u16* __restrict__ xpool,
        u16* __restrict__ tokf, u16* __restrict__ kF, u16* __restrict__ vF) {
    __shared__ u16 pt[64 * 72];
    __shared__ u16 qt[64 * 72];
    int tid = threadIdx.x, id = blockIdx.x;
    int w = tid >> 6, lane = tid & 63, l15 = lane & 15, q4 = lane >> 4;
    f32x4 acc[4];
    if (id < 3456) {
        int px = id % 12, qy = (id / 12) % 144, b = id / 1728;
        gemm64_body<CH>(WT768 + (size_t)px * 64 * CH,
                        xT + ((size_t)b * NTOK + qy * 64) * CH, pt, qt, tid, acc);
        #pragma unroll
        for (int qg = 0; qg < 4; qg++) {
            int q = qy * 64 + qg * 16 + l15;
            int p = px * 64 + w * 16 + q4 * 4;
            uint2 pk;
            pk.x = (unsigned)f2bf(acc[qg][0]) | ((unsigned)f2bf(acc[qg][1]) << 16);
            pk.y = (unsigned)f2bf(acc[qg][2]) | ((unsigned)f2bf(acc[qg][3]) << 16);
            *(uint2*)&tokf[((size_t)b * NTOK + q) * 768 + p] = pk;
        }
    } else if (id < 3672) {
        int u = id - 3456;
        int px = u % 3, qy = (u / 3) % 36, b = u / 108;
        gemm64_body<CH>(WlkT + (size_t)px * 64 * CH,
                        xpool + ((size_t)b * G + qy * 64) * CH, pt, qt, tid, acc);
        #pragma unroll
        for (int qg = 0; qg < 4; qg++) {
            int m = qy * 64 + qg * 16 + l15;
            int d = px * 64 + w * 16 + q4 * 4;
            int h = d >> 5, dh = (d >> 4) & 1, hi2 = (d >> 3) & 1;
            int kh = (m >> 5) & 1, tile = m >> 6, slot = kh * 2 + dh;
            int lane2 = (m & 31) + 32 * hi2;
            size_t addr = ((((size_t)(b * HEADS + h) * NT + tile) * 4 + slot) * 64 + lane2) * 8 + (d & 7);
            uint2 pk;
            pk.x = (unsigned)f2bf(acc[qg][0]) | ((unsigned)f2bf(acc[qg][1]) << 16);
            pk.y = (unsigned)f2bf(acc[qg][2]) | ((unsigned)f2bf(acc[qg][3]) << 16);
            *(uint2*)&kF[addr] = pk;
        }
    } else {
        int u = id - 3672;
        int px = u % 36, qy = (u / 36) % 3, b = u / 108;
        gemm64_body<CH>(xpool + ((size_t)b * G + px * 64) * CH,
                        WvT + (size_t)qy * 64 * CH, pt, qt, tid, acc);
        #pragma unroll
        for (int qg = 0; qg < 4; qg++) {
            int jj = qy * 64 + qg * 16 + l15;
            int m = px * 64 + w * 16 + q4 * 4;
            int h = jj >> 5, d31 = jj & 31;
            int tile = m >> 6, slot = (m >> 4) & 3, hi2 = (m >> 3) & 1;
            int lane2 = d31 + 32 * hi2;
            size_t addr = ((((size_t)(b * HEADS + h) * NT + tile) * 4 + slot) * 64 + lane2) * 8 + (m & 7);
            uint2 pk;
            pk.x = (unsigned)f2bf(acc[qg][0]) | ((unsigned)f2bf(acc[qg][1]) << 16);
            pk.y = (unsigned)f2bf(acc[qg][2]) | ((unsigned)f2bf(acc[qg][3]) << 16);
            *(uint2*)&vF[addr] = pk;
        }
    }
}

// ---------------------------------------------------------------------------
// mega_attn: 256 thr, 5760 blocks interleaved 3 lo : 2 hi via id%5.
// lo (3456): 4 waves = 4-way key split, 9 tiles, 32 q/block; MFMA row-sums;
//   kb A/B register prefetch; s_setprio(1) around per-tile compute (T5).
// hi (2304): TWO windows per block — threads 0-127 / 128-255 each own one.
// NOTE r16: __launch_bounds__(256,8) spills (VGPR->32, 9x slower). Keep (,4).
// ---------------------------------------------------------------------------
__global__ __launch_bounds__(256, 4) void mega_attn(const u16* __restrict__ tokf,
        const u16* __restrict__ kF, const u16* __restrict__ vF,
        u16* __restrict__ hi_ao, u16* __restrict__ lo_ao) {
    __shared__ float smem[4992];
    int tid = threadIdx.x;
    int grp = blockIdx.x / 5, rem = blockIdx.x % 5;
    const f32x16 zero16 = {0.f,0.f,0.f,0.f,0.f,0.f,0.f,0.f,0.f,0.f,0.f,0.f,0.f,0.f,0.f,0.f};

    if (rem < 3) {
        int lid = grp * 3 + rem;              // 0..3455
        int lane = tid & 63, kq = tid >> 6;   // key-quarter 0..3
        int l31 = lane & 31, hi = lane >> 5;
        int qt = lid % 288, h = (lid / 288) % HEADS, b = lid / 1728;

        const short8v ones = {(short)0x3F80, (short)0x3F80, (short)0x3F80, (short)0x3F80,
                              (short)0x3F80, (short)0x3F80, (short)0x3F80, (short)0x3F80};

        short8v qb0, qb1;
        {
            int nq = qt * 32 + l31;
            const u16* qrow = &tokf[((size_t)b * NTOK + nq) * 768 + 576 + h * 32];
            qb0 = *(const short8v*)&qrow[hi * 8];
            qb1 = *(const short8v*)&qrow[16 + hi * 8];
        }
        f32x16 accO = zero16, accL = zero16;

        const u16* kp = kF + ((size_t)(b * HEADS + h) * NT + kq * 9) * 2048 + lane * 8;
        const u16* vp = vF + ((size_t)(b * HEADS + h) * NT + kq * 9) * 2048 + lane * 8;

        auto process = [&](const short8v* kb, const u16* vc) {
            short8v vb0 = *(const short8v*)(vc);
            short8v vb1 = *(const short8v*)(vc + 512);
            short8v vb2 = *(const short8v*)(vc + 1024);
            short8v vb3 = *(const short8v*)(vc + 1536);

            __builtin_amdgcn_s_setprio(1);
            f32x16 s0 = mfma32(kb[0], qb0, zero16);
            s0 = mfma32(kb[1], qb1, s0);
            unsigned pk0[8];
            #pragma unroll
            for (int i = 0; i < 8; i++)
                pk0[i] = cvtpk_bf16(exp2fast(s0[2 * i]), exp2fast(s0[2 * i + 1]));
            permswap(pk0[0], pk0[2]);
            permswap(pk0[1], pk0[3]);
            permswap(pk0[4], pk0[6]);
            permswap(pk0[5], pk0[7]);

            f32x16 s1 = mfma32(kb[2], qb0, zero16);
            s1 = mfma32(kb[3], qb1, s1);
            unsigned pk1[8];
            #pragma unroll
            for (int i = 0; i < 8; i++)
                pk1[i] = cvtpk_bf16(exp2fast(s1[2 * i]), exp2fast(s1[2 * i + 1]));
            permswap(pk1[0], pk1[2]);
            permswap(pk1[1], pk1[3]);
            permswap(pk1[4], pk1[6]);
            permswap(pk1[5], pk1[7]);

            union { unsigned u[4]; short8v v; } pa;
            pa.u[0] = pk0[0]; pa.u[1] = pk0[1]; pa.u[2] = pk0[2]; pa.u[3] = pk0[3];
            accO = mfma32(pa.v, vb0, accO);
            accL = mfma32(pa.v, ones, accL);
            pa.u[0] = pk0[4]; pa.u[1] = pk0[5]; pa.u[2] = pk0[6]; pa.u[3] = pk0[7];
            accO = mfma32(pa.v, vb1, accO);
            accL = mfma32(pa.v, ones, accL);
            pa.u[0] = pk1[0]; pa.u[1] = pk1[1]; pa.u[2] = pk1[2]; pa.u[3] = pk1[3];
            accO = mfma32(pa.v, vb2, accO);
            accL = mfma32(pa.v, ones, accL);
            pa.u[0] = pk1[4]; pa.u[1] = pk1[5]; pa.u[2] = pk1[6]; pa.u[3] = pk1[7];
            accO = mfma32(pa.v, vb3, accO);
            accL = mfma32(pa.v, ones, accL);
            __builtin_amdgcn_s_setprio(0);
        };

        short8v kbA[4], kbB[4];
        #pragma unroll
        for (int sl = 0; sl < 4; sl++) kbA[sl] = *(const short8v*)&kp[sl * 512];

        #pragma unroll
        for (int i = 0; i < 4; i++) {
            {   // even tile t=2i: uses kbA, prefetch kbB(t=2i+1)
                const u16* kn = kp + (size_t)(2 * i + 1) * 2048;
                #pragma unroll
                for (int sl = 0; sl < 4; sl++) kbB[sl] = *(const short8v*)&kn[sl * 512];
                process(kbA, vp + (size_t)(2 * i) * 2048);
            }
            {   // odd tile t=2i+1: uses kbB, prefetch kbA(t=2i+2)
                const u16* kn = kp + (size_t)(2 * i + 2) * 2048;
                #pragma unroll
                for (int sl = 0; sl < 4; sl++) kbA[sl] = *(const short8v*)&kn[sl * 512];
                process(kbB, vp + (size_t)(2 * i + 1) * 2048);
            }
        }
        process(kbA, vp + (size_t)8 * 2048);   // t=8

        // ---- merge 4 key-quarter waves (pure add: no-max softmax) ----
        float* mO = smem;            // [3][16][64] transposed, conflict-free
        float* mL = smem + 3072;     // [3][32]  (accL lane-redundant per half)
        if (kq) {
            int base = (kq - 1) * 1024;
            #pragma unroll
            for (int r = 0; r < 16; r++) mO[base + r * 64 + lane] = accO[r];
            if (l31 == 0) {
                #pragma unroll
                for (int r = 0; r < 16; r++) mL[(kq - 1) * 32 + hi * 16 + r] = accL[r];
            }
        }
        __syncthreads();
        if (kq == 0) {
            #pragma unroll
            for (int w2 = 0; w2 < 3; w2++) {
                int base = w2 * 1024;
                #pragma unroll
                for (int r = 0; r < 16; r++) {
                    accO[r] += mO[base + r * 64 + lane];
                    accL[r] += mL[w2 * 32 + hi * 16 + r];
                }
            }
            #pragma unroll
            for (int r = 0; r < 16; r++) {
                int qr = (r & 3) + 8 * (r >> 2) + 4 * hi;
                int n = qt * 32 + qr;
                lo_ao[((size_t)b * NTOK + n) * 192 + h * 32 + l31] =
                    f2bf(accO[r] * rcpfast(accL[r]));
            }
        }
    } else {
        // ---- hi: 2 windows per block, threads 0-127 / 128-255 ----
        int tid2 = tid & 127, win = tid >> 7;
        int bg = grp * 4 + (rem - 3) * 2 + win;   // 0..4607
        int b = bg / G, g = bg % G;
        int gy = g / GW, gx = g % GW;
        float* s = smem + win * 2496;
        float (*sq)[576] = (float(*)[576])s;
        float* satt = s + 2304;   // [6][4][4]
        float* sp   = s + 2400;   // [6][4][4]

        for (int c = tid2; c < 288; c += 128) {
            int t = c / 72, j8 = c - t * 72;
            int n = (gy * 2 + (t >> 1)) * WW + gx * 2 + (t & 1);
            uint4 u = *(const uint4*)&tokf[((size_t)b * NTOK + n) * 768 + j8 * 8];
            unpack8(u, &sq[t][j8 * 8]);
        }
        __syncthreads();

        if (tid2 < 96) {
            int h = tid2 >> 4, tq = (tid2 >> 2) & 3, tm = tid2 & 3;
            const float* qp = &sq[tq][h * 32];
            const float* kp = &sq[tm][192 + h * 32];
            float s0 = 0, s1 = 0, s2 = 0, s3 = 0;
            #pragma unroll
            for (int d = 0; d < 32; d += 4) {
                s0 += qp[d] * kp[d];
                s1 += qp[d + 1] * kp[d + 1];
                s2 += qp[d + 2] * kp[d + 2];
                s3 += qp[d + 3] * kp[d + 3];
            }
            satt[h * 16 + tq * 4 + tm] = (s0 + s1 + s2 + s3) * SCALE;
        }
        __syncthreads();
        if (tid2 < 24) {
            int h = tid2 >> 2, t = tid2 & 3;
            float l0 = satt[h * 16 + t * 4 + 0], l1 = satt[h * 16 + t * 4 + 1];
            float l2 = satt[h * 16 + t * 4 + 2], l3 = satt[h * 16 + t * 4 + 3];
            float mx = fmaxf(fmaxf(l0, l1), fmaxf(l2, l3));
            float e0 = __expf(l0 - mx), e1 = __expf(l1 - mx);
            float e2 = __expf(l2 - mx), e3 = __expf(l3 - mx);
            float inv = 1.0f / (e0 + e1 + e2 + e3);
            sp[h * 16 + t * 4 + 0] = e0 * inv; sp[h * 16 + t * 4 + 1] = e1 * inv;
            sp[h * 16 + t * 4 + 2] = e2 * inv; sp[h * 16 + t * 4 + 3] = e3 * inv;
        }
        __syncthreads();
        {
            int t = tid2 >> 5, d = tid2 & 31;
            int n = (gy * 2 + (t >> 1)) * WW + gx * 2 + (t & 1);
            u16* op = &hi_ao[((size_t)b * NTOK + n) * 192];
            #pragma unroll
            for (int h = 0; h < HEADS; h++) {
                float o = sp[h * 16 + t * 4 + 0] * sq[0][384 + h * 32 + d]
                        + sp[h * 16 + t * 4 + 1] * sq[1][384 + h * 32 + d]
                        + sp[h * 16 + t * 4 + 2] * sq[2][384 + h * 32 + d]
                        + sp[h * 16 + t * 4 + 3] * sq[3][384 + h * 32 + d];
                op[h * 32 + d] = f2bf(o);
            }
        }
    }
}

// ---------------------------------------------------------------------------
// proj_both: both projections, grid (144, 3, 4): z = which*2 + b.
// ---------------------------------------------------------------------------
__global__ __launch_bounds__(256) void proj_both(const u16* __restrict__ hi_ao,
        const u16* __restrict__ lo_ao, const u16* __restrict__ WhpT,
        const u16* __restrict__ WlpT, const float* __restrict__ bh,
        const float* __restrict__ bl, float* __restrict__ out) {
    __shared__ u16 pt[64 * 72];
    __shared__ u16 qt[64 * 72];
    int tid = threadIdx.x;
    int z = blockIdx.z, which = z >> 1, b = z & 1;
    const u16* A = which ? lo_ao : hi_ao;
    const u16* W = which ? WlpT : WhpT;
    const float* bias = which ? bl : bh;
    int p0 = blockIdx.x * 64, q0 = blockIdx.y * 64;
    f32x4 acc[4];
    gemm64_body<192>(A + ((size_t)b * NTOK + p0) * 192, W + (size_t)q0 * 192,
                     pt, qt, tid, acc);
    int w = tid >> 6, lane = tid & 63, l15 = lane & 15, q4 = lane >> 4;
    #pragma unroll
    for (int qg = 0; qg < 4; qg++) {
        int q = q0 + qg * 16 + l15;
        int p = p0 + w * 16 + q4 * 4;
        float bb = bias[q];
        float4 o = make_float4(acc[qg][0] + bb, acc[qg][1] + bb,
                               acc[qg][2] + bb, acc[qg][3] + bb);
        *(float4*)&out[((size_t)b * CH + which * 192 + q) * NTOK + p] = o;
    }
}

// ---------------------------------------------------------------------------
extern "C" void kernel_launch(void* const* d_in, const int* in_sizes, int n_in,
                              void* d_out, int out_size, void* d_ws, size_t ws_size,
                              hipStream_t stream) {
    const float* x       = (const float*)d_in[0];
    const float* Wh_qkv  = (const float*)d_in[1];
    const float* Wh_proj = (const float*)d_in[2];
    const float* bh_proj = (const float*)d_in[3];
    const float* Wl_q    = (const float*)d_in[4];
    const float* Wl_kv   = (const float*)d_in[5];
    const float* Wl_proj = (const float*)d_in[6];
    const float* bl_proj = (const float*)d_in[7];
    float* out = (float*)d_out;

    // ---- workspace layout (bytes) ----
    char* ws = (char*)d_ws;
    u16*   tokf  = (u16*)ws;                               // [2][9216][768] bf16  28,311,552
    char*  ws1   = ws + (size_t)28311552;
    u16*   xT    = (u16*)ws1;                              // [2][9216][384] bf16  14,155,776
    u16*   hi_ao = (u16*)ws1;                              // overlay (xT dead after gemm_all)
    u16*   lo_ao = (u16*)(ws1 + 7077888);
    char*  ws2   = ws1 + (size_t)14155776;
    u16*   kF    = (u16*)ws2;                              // frag-major K  1,769,472
    u16*   vF    = (u16*)(ws2 + 1769472);                  // frag-major V  1,769,472
    char*  ws3   = ws2 + (size_t)7077888;
    u16*   xpool = (u16*)ws3;                              // [2][2304][384] bf16  3,538,944
    char*  ws4   = ws3 + (size_t)3538944;
    u16*   WT768 = (u16*)ws4;                              // [768][384]
    u16*   WlkvT = WT768 + 768 * 384;                      // [384][384]
    u16*   WhpT  = WlkvT + 384 * 384;                      // [192][192]
    u16*   WlpT  = WhpT + 192 * 192;                       // [192][192]
    u16*   WlkT  = WlkvT;                                  // rows 0..191
    u16*   WvT   = WlkvT + 192 * 384;                      // rows 192..383

    prep<<<dim3(9144), 256, 0, stream>>>(
        x, Wh_qkv, Wl_q, Wl_kv, Wh_proj, Wl_proj,
        xT, xpool, WT768, WT768 + 576 * 384, WlkvT, WhpT, WlpT);

    gemm_all<<<dim3(3888), 256, 0, stream>>>(
        WT768, xT, WlkT, WvT, xpool, tokf, kF, vF);

    mega_attn<<<dim3(5760), 256, 0, stream>>>(tokf, kF, vF, hi_ao, lo_ao);

    proj_both<<<dim3(144, 3, 4), 256, 0, stream>>>(
        hi_ao, lo_ao, WhpT, WlpT, bh_proj, bl_proj, out);
}